// Round 14
// baseline (146.375 us; speedup 1.0000x reference)
//
#include <hip/hip_runtime.h>

#define NN 50000
#define DIM 64
#define NE 1250000
#define NPARTS 196  // ceil(50000/256)

// ---- counting-sort CSR build: 64 edge-slices x 8 row-ranges ----
#define NSL 64
#define SLICEB 19532          // ceil(NE / NSL)
#define RANGE 6250            // NN / 8 rows per range
#define CSTRIDE 50048         // padded row stride of cnt matrix

// bf16 helpers (RNE pack, cheap unpack)
__device__ __forceinline__ unsigned short f2b(float f) {
    unsigned int b = __builtin_bit_cast(unsigned int, f);
    b = (b + 0x7fffu + ((b >> 16) & 1u)) >> 16;
    return (unsigned short)b;
}
__device__ __forceinline__ float blo(unsigned int u) {
    return __builtin_bit_cast(float, u << 16);
}
__device__ __forceinline__ float bhi(unsigned int u) {
    return __builtin_bit_cast(float, u & 0xffff0000u);
}

// ---------------- fp32 -> bf16 pack of the embedding table ----------------
__global__ __launch_bounds__(256) void k_cvt(const float* __restrict__ in,
                                             unsigned short* __restrict__ out) {
    int t = blockIdx.x * blockDim.x + threadIdx.x;  // 8 elems per thread
    if (t >= NN * DIM / 8) return;
    const float4* p = (const float4*)in + t * 2;
    float4 a = p[0], b = p[1];
    ushort4 u0 = {f2b(a.x), f2b(a.y), f2b(a.z), f2b(a.w)};
    ushort4 u1 = {f2b(b.x), f2b(b.y), f2b(b.z), f2b(b.w)};
    ((ushort4*)out)[t * 2 + 0] = u0;
    ((ushort4*)out)[t * 2 + 1] = u1;
}

// ---------------- per-slice LDS histogram (NO global atomics) ----------------
// bid -> slice s = (bid&7)|((bid>>6)<<3), range rng = (bid>>3)&7.
// bid%8 == s%8 -> same-slice blocks on one XCD: slice read into L2 once.
__global__ __launch_bounds__(512) void k_hist(const int* __restrict__ row,
                                              unsigned short* __restrict__ cnt) {
    __shared__ int h[RANGE];
    int bid = blockIdx.x;
    int s   = (bid & 7) | ((bid >> 6) << 3);
    int rng = (bid >> 3) & 7;
    int lo = rng * RANGE;
    int tid = threadIdx.x;
    for (int i = tid; i < RANGE; i += 512) h[i] = 0;
    __syncthreads();
    int beg = s * SLICEB;
    int end = beg + SLICEB;
    if (end > NE) end = NE;
    for (int e = beg + tid; e < end; e += 512) {
        int r = row[e] - lo;
        if ((unsigned)r < RANGE) atomicAdd(&h[r], 1);  // LDS atomic
    }
    __syncthreads();
    unsigned short* c = cnt + s * CSTRIDE + lo;
    for (int i = tid; i < RANGE; i += 512) c[i] = (unsigned short)h[i];
}

// ---------------- per-row scan over slices: cnt -> rel offsets, deg ----------------
__global__ __launch_bounds__(256) void k_rowscan(unsigned short* __restrict__ cnt,
                                                 int* __restrict__ deg) {
    int r = blockIdx.x * blockDim.x + threadIdx.x;
    if (r >= NN) return;
    int acc = 0;
#pragma unroll
    for (int s = 0; s < NSL; ++s) {
        int c = cnt[s * CSTRIDE + r];
        cnt[s * CSTRIDE + r] = (unsigned short)acc;  // exclusive within-row offset
        acc += c;
    }
    deg[r] = acc;
}

// ---------------- hierarchical exclusive scan over deg -> offs ----------------
__global__ __launch_bounds__(256) void k_scan_part(const int* __restrict__ deg,
                                                   int* __restrict__ partial) {
    __shared__ int s[256];
    int t = threadIdx.x;
    int i = blockIdx.x * 256 + t;
    s[t] = (i < NN) ? deg[i] : 0;
    __syncthreads();
    for (int off = 128; off > 0; off >>= 1) {
        if (t < off) s[t] += s[t + off];
        __syncthreads();
    }
    if (t == 0) partial[blockIdx.x] = s[0];
}

__global__ __launch_bounds__(256) void k_scan_top(int* __restrict__ partial) {
    __shared__ int s[256];
    int t = threadIdx.x;
    int v = (t < NPARTS) ? partial[t] : 0;
    s[t] = v;
    __syncthreads();
    for (int off = 1; off < 256; off <<= 1) {
        int x = (t >= off) ? s[t - off] : 0;
        __syncthreads();
        s[t] += x;
        __syncthreads();
    }
    if (t < NPARTS) partial[t] = s[t] - v;
}

__global__ __launch_bounds__(256) void k_scan_final(const int* __restrict__ deg,
                                                    const int* __restrict__ partial,
                                                    int* __restrict__ offs) {
    __shared__ int s[256];
    int t = threadIdx.x;
    int i = blockIdx.x * 256 + t;
    int v = (i < NN) ? deg[i] : 0;
    s[t] = v;
    __syncthreads();
    for (int off = 1; off < 256; off <<= 1) {
        int x = (t >= off) ? s[t - off] : 0;
        __syncthreads();
        s[t] += x;
        __syncthreads();
    }
    int excl = s[t] - v;
    if (i <= NN) offs[i] = partial[blockIdx.x] + excl;  // offs[NN] = NE
}

// ---------------- CSR fill via LDS cursor (NO global atomics) ----------------
// bid -> s = bid>>3, rng = bid&7: bid%8 == rng, so ALL 64 blocks writing a
// given range's csr region run on ONE XCD -> csr lines accumulate dirty in
// that XCD's L2 and evict as FULL lines (kills the 10x write amplification
// measured in round 13: WRITE 48MB for 5MB payload). The slice-read reuse
// lost by this mapping is absorbed by L3 (row/col = 10MB, resident).
__global__ __launch_bounds__(512) void k_fillb(const int* __restrict__ row,
                                               const int* __restrict__ col,
                                               const int* __restrict__ offs,
                                               const unsigned short* __restrict__ cnt,
                                               int* __restrict__ csr) {
    __shared__ int cur[RANGE];
    int bid = blockIdx.x;
    int s   = bid >> 3;
    int rng = bid & 7;
    int lo = rng * RANGE;
    int tid = threadIdx.x;
    const unsigned short* c = cnt + s * CSTRIDE + lo;
    const int* o = offs + lo;
    for (int i = tid; i < RANGE; i += 512) cur[i] = o[i] + c[i];
    __syncthreads();
    int beg = s * SLICEB;
    int end = beg + SLICEB;
    if (end > NE) end = NE;
    for (int e = beg + tid; e < end; e += 512) {
        int r = row[e] - lo;
        if ((unsigned)r < RANGE) {
            int pos = atomicAdd(&cur[r], 1);  // LDS atomic
            csr[pos] = col[e];
        }
    }
}

// ---------------- one propagation layer (bf16 gather, fp32 accum) ----------------
// 4 nodes per wave: lane>>4 = node in wave, lane&15 = feature-quad (uint2 load).
template <int PHASE>
__global__ __launch_bounds__(256) void k_layer(const unsigned short* __restrict__ xin16,
                                               const float* __restrict__ emb,
                                               unsigned short* __restrict__ xout16,
                                               float* __restrict__ out,
                                               const int* __restrict__ offs,
                                               const int* __restrict__ csr) {
    int wid = (blockIdx.x * blockDim.x + threadIdx.x) >> 6;
    int lane = threadIdx.x & 63;
    int sub = lane >> 4;    // node within wave (0..3)
    int sl = lane & 15;     // feature-quad index (0..15)
    int n = 4 * wid + sub;
    if (n >= NN) return;
    int beg = offs[n];
    int end = offs[n + 1];
    const unsigned short* xq = xin16 + sl * 4;

    float a0 = 0.f, a1 = 0.f, a2 = 0.f, a3 = 0.f;
    float b0 = 0.f, b1 = 0.f, b2 = 0.f, b3 = 0.f;
    int e = beg;
    for (; e + 8 <= end; e += 8) {
        int c0 = csr[e + 0], c1 = csr[e + 1], c2 = csr[e + 2], c3 = csr[e + 3];
        int c4 = csr[e + 4], c5 = csr[e + 5], c6 = csr[e + 6], c7 = csr[e + 7];
        uint2 u0 = *(const uint2*)(xq + c0 * DIM);
        uint2 u1 = *(const uint2*)(xq + c1 * DIM);
        uint2 u2 = *(const uint2*)(xq + c2 * DIM);
        uint2 u3 = *(const uint2*)(xq + c3 * DIM);
        uint2 u4 = *(const uint2*)(xq + c4 * DIM);
        uint2 u5 = *(const uint2*)(xq + c5 * DIM);
        uint2 u6 = *(const uint2*)(xq + c6 * DIM);
        uint2 u7 = *(const uint2*)(xq + c7 * DIM);
        a0 += blo(u0.x) + blo(u4.x);  b0 += blo(u1.x) + blo(u5.x);
        a1 += bhi(u0.x) + bhi(u4.x);  b1 += bhi(u1.x) + bhi(u5.x);
        a2 += blo(u0.y) + blo(u4.y);  b2 += blo(u1.y) + blo(u5.y);
        a3 += bhi(u0.y) + bhi(u4.y);  b3 += bhi(u1.y) + bhi(u5.y);
        a0 += blo(u2.x) + blo(u6.x);  b0 += blo(u3.x) + blo(u7.x);
        a1 += bhi(u2.x) + bhi(u6.x);  b1 += bhi(u3.x) + bhi(u7.x);
        a2 += blo(u2.y) + blo(u6.y);  b2 += blo(u3.y) + blo(u7.y);
        a3 += bhi(u2.y) + bhi(u6.y);  b3 += bhi(u3.y) + bhi(u7.y);
    }
    for (; e < end; ++e) {
        uint2 u = *(const uint2*)(xq + csr[e] * DIM);
        a0 += blo(u.x);
        a1 += bhi(u.x);
        a2 += blo(u.y);
        a3 += bhi(u.y);
    }

    int d = end - beg;
    float inv = (d > 0) ? 1.0f / (float)d : 0.0f;
    float v0 = (a0 + b0) * inv;
    float v1 = (a1 + b1) * inv;
    float v2 = (a2 + b2) * inv;
    float v3 = (a3 + b3) * inv;

    int o = n * DIM + sl * 4;
    if (PHASE == 0) {
        float4 ev = *(const float4*)(emb + o);
        float4 ov = {0.25f * (ev.x + v0), 0.25f * (ev.y + v1),
                     0.25f * (ev.z + v2), 0.25f * (ev.w + v3)};
        *(float4*)(out + o) = ov;
        uint2 pk = {(unsigned int)f2b(v0) | ((unsigned int)f2b(v1) << 16),
                    (unsigned int)f2b(v2) | ((unsigned int)f2b(v3) << 16)};
        *(uint2*)(xout16 + o) = pk;
    } else if (PHASE == 1) {
        float4 cur = *(const float4*)(out + o);
        cur.x += 0.25f * v0;
        cur.y += 0.25f * v1;
        cur.z += 0.25f * v2;
        cur.w += 0.25f * v3;
        *(float4*)(out + o) = cur;
        uint2 pk = {(unsigned int)f2b(v0) | ((unsigned int)f2b(v1) << 16),
                    (unsigned int)f2b(v2) | ((unsigned int)f2b(v3) << 16)};
        *(uint2*)(xout16 + o) = pk;
    } else {
        float4 cur = *(const float4*)(out + o);
        cur.x += 0.25f * v0;
        cur.y += 0.25f * v1;
        cur.z += 0.25f * v2;
        cur.w += 0.25f * v3;
        *(float4*)(out + o) = cur;
    }
}

extern "C" void kernel_launch(void* const* d_in, const int* in_sizes, int n_in,
                              void* d_out, int out_size, void* d_ws, size_t ws_size,
                              hipStream_t stream) {
    const int* edge = (const int*)d_in[0];
    const int* row = edge;        // edge_index[0]
    const int* col = edge + NE;   // edge_index[1]
    const float* emb = (const float*)d_in[1];
    float* out = (float*)d_out;

    // workspace layout (~31 MB)
    int* deg    = (int*)d_ws;                                // 50048 ints
    int* offs   = deg + 50048;                               // 50112 ints
    int* partial= offs + 50112;                              // 256 ints
    int* csr    = partial + 256;                             // 1250048 ints
    unsigned short* cnt = (unsigned short*)(csr + 1250048);  // 64*50048 ushort (6.4MB)
    unsigned short* x0  = cnt + NSL * CSTRIDE;               // 3.2M ushort
    unsigned short* xa  = x0 + NN * DIM;
    unsigned short* xb  = xa + NN * DIM;

    k_cvt       <<<(NN * DIM / 8 + 255) / 256, 256, 0, stream>>>(emb, x0);
    k_hist      <<<NSL * 8, 512, 0, stream>>>(row, cnt);
    k_rowscan   <<<NPARTS, 256, 0, stream>>>(cnt, deg);
    k_scan_part <<<NPARTS, 256, 0, stream>>>(deg, partial);
    k_scan_top  <<<1, 256, 0, stream>>>(partial);
    k_scan_final<<<NPARTS, 256, 0, stream>>>(deg, partial, offs);
    k_fillb     <<<NSL * 8, 512, 0, stream>>>(row, col, offs, cnt, csr);

    // 4 nodes per wave: 12500 waves -> 3125 blocks of 256
    int layer_blocks = (NN / 4 * 64) / 256;  // 3125
    k_layer<0><<<layer_blocks, 256, 0, stream>>>(x0, emb, xa, out, offs, csr);
    k_layer<1><<<layer_blocks, 256, 0, stream>>>(xa, nullptr, xb, out, offs, csr);
    k_layer<2><<<layer_blocks, 256, 0, stream>>>(xb, nullptr, nullptr, out, offs, csr);
}